// Round 3
// baseline (363.978 us; speedup 1.0000x reference)
//
#include <hip/hip_runtime.h>
#include <stdint.h>

typedef _Float16 h8v __attribute__((ext_vector_type(8)));
typedef float f4v __attribute__((ext_vector_type(4)));
typedef _Float16 f16;

#define NB 8
#define CC 128
#define CB 64
#define NN 4096

// load 8 consecutive fp32, convert to fp16 MFMA fragment (two 16B loads)
__device__ __forceinline__ h8v ld8f(const float* __restrict__ p){
    const f4v a = *(const f4v*)p;
    const f4v b = *(const f4v*)(p + 4);
    h8v r;
    r[0] = (f16)a[0]; r[1] = (f16)a[1]; r[2] = (f16)a[2]; r[3] = (f16)a[3];
    r[4] = (f16)b[0]; r[5] = (f16)b[1]; r[6] = (f16)b[2]; r[7] = (f16)b[3];
    return r;
}

// ---------------------------------------------------------------------------
// Kernel 1: projections (fp32 in -> fp16 intermediates).
// thetaT/phiT: [b][n][64] (contiguous k -> fragment = one 16B load).
// g: [b][k][m] (m-major, what the PV B-fragment wants).
// ---------------------------------------------------------------------------
__global__ __launch_bounds__(256) void proj_kernel(
    const float* __restrict__ x, const float* __restrict__ wth,
    const float* __restrict__ wph, const float* __restrict__ wg,
    f16* __restrict__ thetaT, f16* __restrict__ phiT, f16* __restrict__ gbuf)
{
    __shared__ __align__(16) f16 xT[64][136];   // x^T tile [n][c] in fp16
    const int b  = blockIdx.x >> 6;
    const int n0 = (blockIdx.x & 63) << 6;
    const int t  = threadIdx.x;

    // stage x^T: coalesced float4 along n, transpose+convert into LDS
    #pragma unroll
    for (int i = 0; i < 8; i++){
        int v  = t + 256 * i;            // 0..2047 float4 slots
        int c  = v >> 4;
        int j0 = (v & 15) << 2;
        const f4v xv = *(const f4v*)&x[((size_t)(b * CC + c)) * NN + n0 + j0];
        #pragma unroll
        for (int jj = 0; jj < 4; jj++) xT[j0 + jj][c] = (f16)xv[jj];
    }
    __syncthreads();

    const int w = t >> 6, lane = t & 63, quad = lane >> 4, l15 = lane & 15;

    // A-frags (x^T rows for this wave's n-subtile), K=128 -> 4 chunks
    h8v a[4];
    #pragma unroll
    for (int kc = 0; kc < 4; kc++)
        a[kc] = *(const h8v*)&xT[w * 16 + l15][kc * 32 + quad * 8];

    // theta & phi: D^T = x^T * W^T orientation; wave w owns n-subtile w
    #pragma unroll
    for (int m3 = 0; m3 < 2; m3++){
        const float* W = (m3 == 0) ? wth : wph;
        f16* OUT       = (m3 == 0) ? thetaT : phiT;
        for (int ks = 0; ks < 4; ks++){
            f4v acc = {0.f, 0.f, 0.f, 0.f};
            #pragma unroll
            for (int kc = 0; kc < 4; kc++){
                const h8v bf = ld8f(&W[(ks * 16 + l15) * CC + kc * 32 + quad * 8]);
                acc = __builtin_amdgcn_mfma_f32_16x16x32_f16(a[kc], bf, acc, 0, 0, 0);
            }
            #pragma unroll
            for (int r = 0; r < 4; r++){
                int nl = w * 16 + quad * 4 + r;
                int k  = ks * 16 + l15;
                OUT[((size_t)(b * NN + n0 + nl)) * CB + k] = (f16)acc[r];
            }
        }
    }

    // g: D = W * x orientation (writes m-major/coalesced); wave w owns k-subtile w
    h8v aw[4];
    #pragma unroll
    for (int kc = 0; kc < 4; kc++)
        aw[kc] = ld8f(&wg[(w * 16 + l15) * CC + kc * 32 + quad * 8]);
    for (int ns = 0; ns < 4; ns++){
        f4v acc = {0.f, 0.f, 0.f, 0.f};
        #pragma unroll
        for (int kc = 0; kc < 4; kc++){
            const h8v bx = *(const h8v*)&xT[ns * 16 + l15][kc * 32 + quad * 8];
            acc = __builtin_amdgcn_mfma_f32_16x16x32_f16(aw[kc], bx, acc, 0, 0, 0);
        }
        #pragma unroll
        for (int r = 0; r < 4; r++){
            int k = w * 16 + quad * 4 + r;
            int n = n0 + ns * 16 + l15;
            gbuf[((size_t)(b * CB + k)) * NN + n] = (f16)acc[r];
        }
    }
}

// ---------------------------------------------------------------------------
// Kernel 2: flash attention over spatial positions. 4 waves/block, 16 queries
// per wave, 64-key chunks, online softmax. P round-trips through wave-private
// LDS to convert C/D layout -> A-operand layout.
// ---------------------------------------------------------------------------
__global__ __launch_bounds__(256) void attn_kernel(
    const f16* __restrict__ thetaT, const f16* __restrict__ phiT,
    const f16* __restrict__ gbuf, f16* __restrict__ yT)
{
    __shared__ __align__(16) f16 plds[4][16 * 72];   // per-wave P tile, stride 72
    const int b  = blockIdx.x >> 6;
    const int q0 = (blockIdx.x & 63) << 6;
    const int t  = threadIdx.x;
    const int w = t >> 6, lane = t & 63, quad = lane >> 4, l15 = lane & 15;
    const int n0 = q0 + w * 16;

    // A-frags (theta^T rows), loaded once, reused for all key chunks
    const h8v a0 = *(const h8v*)&thetaT[((size_t)(b * NN + n0 + l15)) * CB + quad * 8];
    const h8v a1 = *(const h8v*)&thetaT[((size_t)(b * NN + n0 + l15)) * CB + 32 + quad * 8];

    float mrun[4], lrun[4];
    f4v o[4];
    const f4v zf = {0.f, 0.f, 0.f, 0.f};
    #pragma unroll
    for (int r = 0; r < 4; r++){ mrun[r] = -1e30f; lrun[r] = 0.f; }
    #pragma unroll
    for (int tt = 0; tt < 4; tt++) o[tt] = zf;

    for (int kb = 0; kb < 64; kb++){
        const int m0 = kb * 64;
        // S = theta^T phi  (16 q x 64 keys)
        f4v s[4];
        #pragma unroll
        for (int tt = 0; tt < 4; tt++){
            const size_t prow = ((size_t)(b * NN + m0 + tt * 16 + l15)) * CB;
            const h8v pb0 = *(const h8v*)&phiT[prow + quad * 8];
            const h8v pb1 = *(const h8v*)&phiT[prow + 32 + quad * 8];
            f4v sv = zf;
            sv = __builtin_amdgcn_mfma_f32_16x16x32_f16(a0, pb0, sv, 0, 0, 0);
            sv = __builtin_amdgcn_mfma_f32_16x16x32_f16(a1, pb1, sv, 0, 0, 0);
            s[tt] = sv;
        }
        // online softmax: row max across the 16 lanes of each quad
        float rmax[4];
        #pragma unroll
        for (int r = 0; r < 4; r++)
            rmax[r] = fmaxf(fmaxf(s[0][r], s[1][r]), fmaxf(s[2][r], s[3][r]));
        #pragma unroll
        for (int mask = 1; mask <= 8; mask <<= 1){
            #pragma unroll
            for (int r = 0; r < 4; r++)
                rmax[r] = fmaxf(rmax[r], __shfl_xor(rmax[r], mask));
        }
        float alpha[4];
        #pragma unroll
        for (int r = 0; r < 4; r++){
            float mn = fmaxf(mrun[r], rmax[r]);
            alpha[r] = __expf(mrun[r] - mn);
            mrun[r]  = mn;
            lrun[r] *= alpha[r];
        }
        #pragma unroll
        for (int tt = 0; tt < 4; tt++){
            #pragma unroll
            for (int r = 0; r < 4; r++){
                float p = __expf(s[tt][r] - mrun[r]);
                lrun[r] += p;
                plds[w][(quad * 4 + r) * 72 + tt * 16 + l15] = (f16)p;
                o[tt][r] *= alpha[r];
            }
        }
        // reload P as A-operand fragments (wave-private -> same-wave DS ordering)
        const h8v pa0 = *(const h8v*)&plds[w][l15 * 72 + quad * 8];
        const h8v pa1 = *(const h8v*)&plds[w][l15 * 72 + 32 + quad * 8];
        // O += P * g^T   (g stored [k][m], m-major = B-fragment contiguous)
        #pragma unroll
        for (int tt = 0; tt < 4; tt++){
            const size_t grow = ((size_t)(b * CB + tt * 16 + l15)) * NN + m0;
            const h8v gb0 = *(const h8v*)&gbuf[grow + quad * 8];
            const h8v gb1 = *(const h8v*)&gbuf[grow + 32 + quad * 8];
            o[tt] = __builtin_amdgcn_mfma_f32_16x16x32_f16(pa0, gb0, o[tt], 0, 0, 0);
            o[tt] = __builtin_amdgcn_mfma_f32_16x16x32_f16(pa1, gb1, o[tt], 0, 0, 0);
        }
    }

    // final softmax denominator across the quad's 16 lanes
    #pragma unroll
    for (int mask = 1; mask <= 8; mask <<= 1){
        #pragma unroll
        for (int r = 0; r < 4; r++)
            lrun[r] += __shfl_xor(lrun[r], mask);
    }
    float inv[4];
    #pragma unroll
    for (int r = 0; r < 4; r++) inv[r] = 1.0f / lrun[r];
    #pragma unroll
    for (int tt = 0; tt < 4; tt++){
        #pragma unroll
        for (int r = 0; r < 4; r++){
            int q = quad * 4 + r;
            yT[((size_t)(b * NN + n0 + q)) * CB + tt * 16 + l15] = (f16)(o[tt][r] * inv[r]);
        }
    }
}

// ---------------------------------------------------------------------------
// Kernel 3: out = w_last * y + x (fp32 out, fp32 residual).
// ---------------------------------------------------------------------------
__global__ __launch_bounds__(256) void out_kernel(
    const float* __restrict__ wl, const f16* __restrict__ yT,
    const float* __restrict__ x, float* __restrict__ out)
{
    const int b  = blockIdx.x >> 6;
    const int n0 = (blockIdx.x & 63) << 6;
    const int t  = threadIdx.x;
    const int w = t >> 6, lane = t & 63, quad = lane >> 4, l15 = lane & 15;

    h8v wlf[2][2];
    #pragma unroll
    for (int cs = 0; cs < 2; cs++)
        #pragma unroll
        for (int kc = 0; kc < 2; kc++)
            wlf[cs][kc] = ld8f(&wl[((w * 2 + cs) * 16 + l15) * CB + kc * 32 + quad * 8]);

    #pragma unroll
    for (int ns = 0; ns < 4; ns++){
        const size_t yrow = ((size_t)(b * NN + n0 + ns * 16 + l15)) * CB;
        const h8v yb0 = *(const h8v*)&yT[yrow + quad * 8];
        const h8v yb1 = *(const h8v*)&yT[yrow + 32 + quad * 8];
        #pragma unroll
        for (int cs = 0; cs < 2; cs++){
            f4v acc = {0.f, 0.f, 0.f, 0.f};
            acc = __builtin_amdgcn_mfma_f32_16x16x32_f16(wlf[cs][0], yb0, acc, 0, 0, 0);
            acc = __builtin_amdgcn_mfma_f32_16x16x32_f16(wlf[cs][1], yb1, acc, 0, 0, 0);
            #pragma unroll
            for (int r = 0; r < 4; r++){
                int c = (w * 2 + cs) * 16 + quad * 4 + r;
                size_t idx = ((size_t)(b * CC + c)) * NN + n0 + ns * 16 + l15;
                out[idx] = acc[r] + x[idx];
            }
        }
    }
}

extern "C" void kernel_launch(void* const* d_in, const int* in_sizes, int n_in,
                              void* d_out, int out_size, void* d_ws, size_t ws_size,
                              hipStream_t stream)
{
    const float* x   = (const float*)d_in[0];
    const float* wth = (const float*)d_in[1];
    const float* wph = (const float*)d_in[2];
    const float* wg  = (const float*)d_in[3];
    const float* wl  = (const float*)d_in[4];
    float* out = (float*)d_out;

    f16* thetaT = (f16*)d_ws;
    f16* phiT   = thetaT + (size_t)NB * NN * CB;
    f16* gbuf   = phiT   + (size_t)NB * NN * CB;
    f16* yT     = gbuf   + (size_t)NB * NN * CB;

    proj_kernel<<<NB * 64, 256, 0, stream>>>(x, wth, wph, wg, thetaT, phiT, gbuf);
    attn_kernel<<<NB * 64, 256, 0, stream>>>(thetaT, phiT, gbuf, yT);
    out_kernel <<<NB * 64, 256, 0, stream>>>(wl, yT, x, out);
}

// Round 4
// 328.994 us; speedup vs baseline: 1.1063x; 1.1063x over previous
//
#include <hip/hip_runtime.h>
#include <stdint.h>

typedef _Float16 h8v __attribute__((ext_vector_type(8)));
typedef float f4v __attribute__((ext_vector_type(4)));
typedef _Float16 f16;

#define NB 8
#define CC 128
#define CB 64
#define NN 4096

// load 8 consecutive fp32, convert to fp16 MFMA fragment (two 16B loads)
__device__ __forceinline__ h8v ld8f(const float* __restrict__ p){
    const f4v a = *(const f4v*)p;
    const f4v b = *(const f4v*)(p + 4);
    h8v r;
    r[0] = (f16)a[0]; r[1] = (f16)a[1]; r[2] = (f16)a[2]; r[3] = (f16)a[3];
    r[4] = (f16)b[0]; r[5] = (f16)b[1]; r[6] = (f16)b[2]; r[7] = (f16)b[3];
    return r;
}

// ---------------------------------------------------------------------------
// Kernel 1: projections (fp32 in -> fp16 intermediates).
// thetaT/phiT: [b][n][64] (contiguous k -> fragment = one 16B load).
// g: [b][k][m] (m-major, what the PV B-fragment wants).
// ---------------------------------------------------------------------------
__global__ __launch_bounds__(256) void proj_kernel(
    const float* __restrict__ x, const float* __restrict__ wth,
    const float* __restrict__ wph, const float* __restrict__ wg,
    f16* __restrict__ thetaT, f16* __restrict__ phiT, f16* __restrict__ gbuf)
{
    __shared__ __align__(16) f16 xT[64][136];   // x^T tile [n][c] in fp16
    const int b  = blockIdx.x >> 6;
    const int n0 = (blockIdx.x & 63) << 6;
    const int t  = threadIdx.x;

    #pragma unroll
    for (int i = 0; i < 8; i++){
        int v  = t + 256 * i;            // 0..2047 float4 slots
        int c  = v >> 4;
        int j0 = (v & 15) << 2;
        const f4v xv = *(const f4v*)&x[((size_t)(b * CC + c)) * NN + n0 + j0];
        #pragma unroll
        for (int jj = 0; jj < 4; jj++) xT[j0 + jj][c] = (f16)xv[jj];
    }
    __syncthreads();

    const int w = t >> 6, lane = t & 63, quad = lane >> 4, l15 = lane & 15;

    h8v a[4];
    #pragma unroll
    for (int kc = 0; kc < 4; kc++)
        a[kc] = *(const h8v*)&xT[w * 16 + l15][kc * 32 + quad * 8];

    #pragma unroll
    for (int m3 = 0; m3 < 2; m3++){
        const float* W = (m3 == 0) ? wth : wph;
        f16* OUT       = (m3 == 0) ? thetaT : phiT;
        for (int ks = 0; ks < 4; ks++){
            f4v acc = {0.f, 0.f, 0.f, 0.f};
            #pragma unroll
            for (int kc = 0; kc < 4; kc++){
                const h8v bf = ld8f(&W[(ks * 16 + l15) * CC + kc * 32 + quad * 8]);
                acc = __builtin_amdgcn_mfma_f32_16x16x32_f16(a[kc], bf, acc, 0, 0, 0);
            }
            #pragma unroll
            for (int r = 0; r < 4; r++){
                int nl = w * 16 + quad * 4 + r;
                int k  = ks * 16 + l15;
                OUT[((size_t)(b * NN + n0 + nl)) * CB + k] = (f16)acc[r];
            }
        }
    }

    h8v aw[4];
    #pragma unroll
    for (int kc = 0; kc < 4; kc++)
        aw[kc] = ld8f(&wg[(w * 16 + l15) * CC + kc * 32 + quad * 8]);
    for (int ns = 0; ns < 4; ns++){
        f4v acc = {0.f, 0.f, 0.f, 0.f};
        #pragma unroll
        for (int kc = 0; kc < 4; kc++){
            const h8v bx = *(const h8v*)&xT[ns * 16 + l15][kc * 32 + quad * 8];
            acc = __builtin_amdgcn_mfma_f32_16x16x32_f16(aw[kc], bx, acc, 0, 0, 0);
        }
        #pragma unroll
        for (int r = 0; r < 4; r++){
            int k = w * 16 + quad * 4 + r;
            int n = n0 + ns * 16 + l15;
            gbuf[((size_t)(b * CB + k)) * NN + n] = (f16)acc[r];
        }
    }
}

// ---------------------------------------------------------------------------
// Kernel 2: flash attention, key-split. One block = 16 queries; each of the
// 4 waves handles 1024 keys (16 chunks of 64) with private online softmax;
// partial (O, m, l) merged in LDS at the end. 2048 blocks -> 8192 waves
// (4x the R3 parallelism) to hide L2 latency.
// ---------------------------------------------------------------------------
__global__ __launch_bounds__(256) void attn_kernel(
    const f16* __restrict__ thetaT, const f16* __restrict__ phiT,
    const f16* __restrict__ gbuf, f16* __restrict__ yT)
{
    __shared__ __align__(16) f16 plds[4][16 * 72];   // per-wave P tile
    __shared__ __align__(16) float oL[4][16][64];    // per-wave partial O
    __shared__ float mwS[4][16], lwS[4][16];

    const int b  = blockIdx.x >> 8;
    const int n0 = (blockIdx.x & 255) << 4;
    const int t  = threadIdx.x;
    const int w = t >> 6, lane = t & 63, quad = lane >> 4, l15 = lane & 15;

    // A-frags (theta^T rows) — same 16 queries for all 4 waves
    const size_t trow = ((size_t)(b * NN + n0 + l15)) * CB;
    const h8v a0 = *(const h8v*)&thetaT[trow + quad * 8];
    const h8v a1 = *(const h8v*)&thetaT[trow + 32 + quad * 8];

    float mrun[4], lrun[4];
    f4v o[4];
    const f4v zf = {0.f, 0.f, 0.f, 0.f};
    #pragma unroll
    for (int r = 0; r < 4; r++){ mrun[r] = -1e30f; lrun[r] = 0.f; }
    #pragma unroll
    for (int tt = 0; tt < 4; tt++) o[tt] = zf;

    const int kbase = w << 10;           // this wave's 1024-key slice
    for (int kb = 0; kb < 16; kb++){
        const int m0 = kbase + kb * 64;
        // batch-issue all 8 phi fragment loads, then the S MFMAs
        h8v pb0[4], pb1[4];
        #pragma unroll
        for (int tt = 0; tt < 4; tt++){
            const size_t prow = ((size_t)(b * NN + m0 + tt * 16 + l15)) * CB;
            pb0[tt] = *(const h8v*)&phiT[prow + quad * 8];
            pb1[tt] = *(const h8v*)&phiT[prow + 32 + quad * 8];
        }
        f4v s[4];
        #pragma unroll
        for (int tt = 0; tt < 4; tt++){
            f4v sv = zf;
            sv = __builtin_amdgcn_mfma_f32_16x16x32_f16(a0, pb0[tt], sv, 0, 0, 0);
            sv = __builtin_amdgcn_mfma_f32_16x16x32_f16(a1, pb1[tt], sv, 0, 0, 0);
            s[tt] = sv;
        }
        // online softmax: row max across the 16 lanes of each quad
        float rmax[4];
        #pragma unroll
        for (int r = 0; r < 4; r++)
            rmax[r] = fmaxf(fmaxf(s[0][r], s[1][r]), fmaxf(s[2][r], s[3][r]));
        #pragma unroll
        for (int mask = 1; mask <= 8; mask <<= 1){
            #pragma unroll
            for (int r = 0; r < 4; r++)
                rmax[r] = fmaxf(rmax[r], __shfl_xor(rmax[r], mask));
        }
        float alpha[4];
        #pragma unroll
        for (int r = 0; r < 4; r++){
            float mn = fmaxf(mrun[r], rmax[r]);
            alpha[r] = __expf(mrun[r] - mn);
            mrun[r]  = mn;
            lrun[r] *= alpha[r];
        }
        #pragma unroll
        for (int tt = 0; tt < 4; tt++){
            #pragma unroll
            for (int r = 0; r < 4; r++){
                float p = __expf(s[tt][r] - mrun[r]);
                lrun[r] += p;
                plds[w][(quad * 4 + r) * 72 + tt * 16 + l15] = (f16)p;
                o[tt][r] *= alpha[r];
            }
        }
        // reload P as A-operand fragments (wave-private -> same-wave DS order)
        const h8v pa0 = *(const h8v*)&plds[w][l15 * 72 + quad * 8];
        const h8v pa1 = *(const h8v*)&plds[w][l15 * 72 + 32 + quad * 8];
        // O += P * g^T
        #pragma unroll
        for (int tt = 0; tt < 4; tt++){
            const size_t grow = ((size_t)(b * CB + tt * 16 + l15)) * NN + m0;
            const h8v gb0 = *(const h8v*)&gbuf[grow + quad * 8];
            const h8v gb1 = *(const h8v*)&gbuf[grow + 32 + quad * 8];
            o[tt] = __builtin_amdgcn_mfma_f32_16x16x32_f16(pa0, gb0, o[tt], 0, 0, 0);
            o[tt] = __builtin_amdgcn_mfma_f32_16x16x32_f16(pa1, gb1, o[tt], 0, 0, 0);
        }
    }

    // reduce denominator across the quad's 16 lanes (per-wave partial)
    #pragma unroll
    for (int mask = 1; mask <= 8; mask <<= 1){
        #pragma unroll
        for (int r = 0; r < 4; r++)
            lrun[r] += __shfl_xor(lrun[r], mask);
    }

    // publish per-wave partial state
    #pragma unroll
    for (int tt = 0; tt < 4; tt++)
        #pragma unroll
        for (int r = 0; r < 4; r++)
            oL[w][quad * 4 + r][tt * 16 + l15] = o[tt][r];
    if (l15 == 0){
        #pragma unroll
        for (int r = 0; r < 4; r++){
            mwS[w][quad * 4 + r] = mrun[r];
            lwS[w][quad * 4 + r] = lrun[r];
        }
    }
    __syncthreads();

    // merge 4 partials: thread t -> col = t&63, rows (t>>6)*4 .. +3
    const int col = t & 63;
    #pragma unroll
    for (int rr = 0; rr < 4; rr++){
        const int row = (t >> 6) * 4 + rr;
        const float m0v = mwS[0][row], m1v = mwS[1][row];
        const float m2v = mwS[2][row], m3v = mwS[3][row];
        const float M = fmaxf(fmaxf(m0v, m1v), fmaxf(m2v, m3v));
        const float e0 = __expf(m0v - M), e1 = __expf(m1v - M);
        const float e2 = __expf(m2v - M), e3 = __expf(m3v - M);
        const float L = lwS[0][row] * e0 + lwS[1][row] * e1
                      + lwS[2][row] * e2 + lwS[3][row] * e3;
        const float val = oL[0][row][col] * e0 + oL[1][row][col] * e1
                        + oL[2][row][col] * e2 + oL[3][row][col] * e3;
        yT[((size_t)(b * NN + n0 + row)) * CB + col] = (f16)(val / L);
    }
}

// ---------------------------------------------------------------------------
// Kernel 3: out = w_last * y + x (fp32 out, fp32 residual).
// ---------------------------------------------------------------------------
__global__ __launch_bounds__(256) void out_kernel(
    const float* __restrict__ wl, const f16* __restrict__ yT,
    const float* __restrict__ x, float* __restrict__ out)
{
    const int b  = blockIdx.x >> 6;
    const int n0 = (blockIdx.x & 63) << 6;
    const int t  = threadIdx.x;
    const int w = t >> 6, lane = t & 63, quad = lane >> 4, l15 = lane & 15;

    h8v wlf[2][2];
    #pragma unroll
    for (int cs = 0; cs < 2; cs++)
        #pragma unroll
        for (int kc = 0; kc < 2; kc++)
            wlf[cs][kc] = ld8f(&wl[((w * 2 + cs) * 16 + l15) * CB + kc * 32 + quad * 8]);

    #pragma unroll
    for (int ns = 0; ns < 4; ns++){
        const size_t yrow = ((size_t)(b * NN + n0 + ns * 16 + l15)) * CB;
        const h8v yb0 = *(const h8v*)&yT[yrow + quad * 8];
        const h8v yb1 = *(const h8v*)&yT[yrow + 32 + quad * 8];
        #pragma unroll
        for (int cs = 0; cs < 2; cs++){
            f4v acc = {0.f, 0.f, 0.f, 0.f};
            acc = __builtin_amdgcn_mfma_f32_16x16x32_f16(wlf[cs][0], yb0, acc, 0, 0, 0);
            acc = __builtin_amdgcn_mfma_f32_16x16x32_f16(wlf[cs][1], yb1, acc, 0, 0, 0);
            #pragma unroll
            for (int r = 0; r < 4; r++){
                int c = (w * 2 + cs) * 16 + quad * 4 + r;
                size_t idx = ((size_t)(b * CC + c)) * NN + n0 + ns * 16 + l15;
                out[idx] = acc[r] + x[idx];
            }
        }
    }
}

extern "C" void kernel_launch(void* const* d_in, const int* in_sizes, int n_in,
                              void* d_out, int out_size, void* d_ws, size_t ws_size,
                              hipStream_t stream)
{
    const float* x   = (const float*)d_in[0];
    const float* wth = (const float*)d_in[1];
    const float* wph = (const float*)d_in[2];
    const float* wg  = (const float*)d_in[3];
    const float* wl  = (const float*)d_in[4];
    float* out = (float*)d_out;

    f16* thetaT = (f16*)d_ws;
    f16* phiT   = thetaT + (size_t)NB * NN * CB;
    f16* gbuf   = phiT   + (size_t)NB * NN * CB;
    f16* yT     = gbuf   + (size_t)NB * NN * CB;

    proj_kernel<<<NB * 64, 256, 0, stream>>>(x, wth, wph, wg, thetaT, phiT, gbuf);
    attn_kernel<<<NB * 256, 256, 0, stream>>>(thetaT, phiT, gbuf, yT);
    out_kernel <<<NB * 64, 256, 0, stream>>>(wl, yT, x, out);
}